// Round 2
// baseline (609.469 us; speedup 1.0000x reference)
//
#include <hip/hip_runtime.h>
#include <hip/hip_bf16.h>

#define HID 768
#define WROW 1536   // merge_w row stride (floats)
#define NLAB 64

typedef __attribute__((ext_vector_type(8))) __bf16 bf16x8;
typedef __attribute__((ext_vector_type(4))) float f32x4;

__device__ __forceinline__ void async16(const void* g, void* l) {
    __builtin_amdgcn_global_load_lds(
        (const __attribute__((address_space(1))) void*)g,
        (__attribute__((address_space(3))) void*)l,
        16, 0, 0);
}

// ---------------------------------------------------------------------------
// Kernel 1: P[l][j] = bias[j] + sum_k lf[l][k] * W[j][HID + k]   (all fp32)
// 64 blocks (one per label) x 256 threads; each thread does 3 j-values.
// W right half (2.25 MiB) is re-read by all 64 blocks -> L2/L3 hits.
// ---------------------------------------------------------------------------
__global__ __launch_bounds__(256) void compute_P_kernel(
    const float* __restrict__ lf,    // [64, 768]
    const float* __restrict__ W,     // [768, 1536]
    const float* __restrict__ bias,  // [768]
    float* __restrict__ P)           // [64, 768]
{
    const int l = blockIdx.x;
    const int t = threadIdx.x;
    __shared__ float lfs[HID];
    for (int i = t; i < HID; i += 256) lfs[i] = lf[l * HID + i];
    __syncthreads();

    #pragma unroll
    for (int jj = 0; jj < 3; ++jj) {
        const int j = jj * 256 + t;
        const float* wr = W + (size_t)j * WROW + HID;
        float acc = bias[j];
        for (int k = 0; k < HID; k += 4) {
            float4 u = *(const float4*)(wr + k);
            acc += lfs[k] * u.x + lfs[k + 1] * u.y
                 + lfs[k + 2] * u.z + lfs[k + 3] * u.w;
        }
        P[l * HID + j] = acc;
    }
}

// ---------------------------------------------------------------------------
// Kernel 2: out[n][j] = (lab==0) ? A[n][j]
//                     : sum_k bf16(A[n][k])*bf16(W[j][k]) + P[lab-1][j]
// 128x128 tile, BK=32, 256 thr = 4 waves, 4x4 mfma 16x16x32 per wave.
// fp32 tiles staged via global_load_lds(16B); XOR-swizzled 16B chunks
// (chunk ^= row&7) applied at the GLOBAL address so LDS dest stays
// lane-contiguous; fragment reads land 2-way (free) instead of 16-way.
// ---------------------------------------------------------------------------
__global__ __launch_bounds__(256) void merge_gemm_kernel(
    const float* __restrict__ A,       // [65536, 768]
    const int* __restrict__ labels,    // [65536]
    const float* __restrict__ W,       // [768, 1536] (left half used)
    const float* __restrict__ P,       // [64, 768]
    float* __restrict__ out)           // [65536, 768]
{
    __shared__ float As[128 * 32];   // 16 KB, [row][32] fp32, chunks swizzled
    __shared__ float Bs[128 * 32];   // 16 KB
    __shared__ int Ls[128];

    const int t  = threadIdx.x;
    const int m0 = blockIdx.y * 128;
    const int j0 = blockIdx.x * 128;

    if (t < 128) Ls[t] = labels[m0 + t];

    const int w  = t >> 6;
    const int l  = t & 63;
    const int lm = l & 15;        // row/col inside 16x16 tile
    const int lk = l >> 4;        // k-group 0..3
    const int qm = (w >> 1) * 64;
    const int qn = (w & 1) * 64;

    f32x4 acc[4][4] = {};

    // Staging map: one async16 issue = 256 thr x 4 floats = 32 rows x 32 cols.
    // Thread t -> row sr = t>>3, swizzled col chunk (t&7)^(sr&7).
    const int sr = t >> 3;                         // 0..31
    const int sc = ((t & 7) ^ (sr & 7)) * 4;       // swizzled float offset
    const float* gA = A + (size_t)(m0 + sr) * HID + sc;
    const float* gB = W + (size_t)(j0 + sr) * WROW + sc;
    float* lA = As + t * 4;
    float* lB = Bs + t * 4;

    for (int k0 = 0; k0 < HID; k0 += 32) {
        #pragma unroll
        for (int i = 0; i < 4; ++i) {
            async16(gA + (size_t)(32 * i) * HID + k0, lA + 1024 * i);
            async16(gB + (size_t)(32 * i) * WROW + k0, lB + 1024 * i);
        }
        __syncthreads();   // compiler emits s_waitcnt vmcnt(0) before barrier

        // Fragment read + cvt. Stored chunk p holds source chunk p^(row&7),
        // so source chunk c is at position c^(row&7).
        bf16x8 af[4], bfr[4];
        #pragma unroll
        for (int mi = 0; mi < 4; ++mi) {
            const int r = qm + mi * 16 + lm;
            const int s = r & 7;
            f32x4 lo = *(const f32x4*)(As + r * 32 + ((2 * lk) ^ s) * 4);
            f32x4 hi = *(const f32x4*)(As + r * 32 + ((2 * lk + 1) ^ s) * 4);
            af[mi] = (bf16x8){(__bf16)lo.x, (__bf16)lo.y, (__bf16)lo.z, (__bf16)lo.w,
                              (__bf16)hi.x, (__bf16)hi.y, (__bf16)hi.z, (__bf16)hi.w};
        }
        #pragma unroll
        for (int ni = 0; ni < 4; ++ni) {
            const int r = qn + ni * 16 + lm;
            const int s = r & 7;
            f32x4 lo = *(const f32x4*)(Bs + r * 32 + ((2 * lk) ^ s) * 4);
            f32x4 hi = *(const f32x4*)(Bs + r * 32 + ((2 * lk + 1) ^ s) * 4);
            bfr[ni] = (bf16x8){(__bf16)lo.x, (__bf16)lo.y, (__bf16)lo.z, (__bf16)lo.w,
                               (__bf16)hi.x, (__bf16)hi.y, (__bf16)hi.z, (__bf16)hi.w};
        }

        #pragma unroll
        for (int mi = 0; mi < 4; ++mi)
            #pragma unroll
            for (int ni = 0; ni < 4; ++ni)
                acc[mi][ni] = __builtin_amdgcn_mfma_f32_16x16x32_bf16(
                    af[mi], bfr[ni], acc[mi][ni], 0, 0, 0);

        __syncthreads();
    }

    // Epilogue. C/D layout: col = lane&15, row = (lane>>4)*4 + reg  [m89/m91]
    #pragma unroll
    for (int mi = 0; mi < 4; ++mi) {
        const int rowb = qm + mi * 16 + lk * 4;
        #pragma unroll
        for (int r = 0; r < 4; ++r) {
            const int n_tok = m0 + rowb + r;
            const int lab   = Ls[rowb + r];
            const size_t rowoff = (size_t)n_tok * HID;
            #pragma unroll
            for (int ni = 0; ni < 4; ++ni) {
                const int j = j0 + qn + ni * 16 + lm;
                float v;
                if (lab != 0)
                    v = acc[mi][ni][r] + P[(size_t)(lab - 1) * HID + j];
                else
                    v = A[rowoff + j];
                out[rowoff + j] = v;
            }
        }
    }
}

extern "C" void kernel_launch(void* const* d_in, const int* in_sizes, int n_in,
                              void* d_out, int out_size, void* d_ws, size_t ws_size,
                              hipStream_t stream) {
    const float* com    = (const float*)d_in[0];  // [16,4096,768] fp32
    const int*   labels = (const int*)d_in[1];    // [16,4096] int32
    const float* lf     = (const float*)d_in[2];  // [64,768] fp32
    const float* W      = (const float*)d_in[3];  // [768,1536] fp32
    const float* bias   = (const float*)d_in[4];  // [768] fp32
    float* out = (float*)d_out;
    float* P = (float*)d_ws;   // 64*768 fp32 = 192 KiB scratch

    const int n_rows = in_sizes[0] / HID;         // 65536
    compute_P_kernel<<<dim3(NLAB), dim3(256), 0, stream>>>(lf, W, bias, P);
    merge_gemm_kernel<<<dim3(HID / 128, n_rows / 128), dim3(256), 0, stream>>>(
        com, labels, W, P, out);
}